// Round 1
// baseline (3572.752 us; speedup 1.0000x reference)
//
#include <hip/hip_runtime.h>
#include <math.h>

// Problem: fused transformer block. B=4, T=2048, C=1024, H=16, D=64. fp32.
// M = B*T = 8192 rows everywhere.
//
// Pipeline:
//   lnbuf = LN(x, ln1)                      [ln_kernel]
//   qkv   = lnbuf @ w_attn + b_attn         [gemm<0>]  (8192x1024)@(1024x3072)
//   ybuf  = causal_flash_attn(qkv)          [flash_kernel]
//   out   = ybuf @ w_proj + b_proj + x      [gemm<1>]  (residual #1)
//   lnbuf = LN(out, ln2)                    [ln_kernel]
//   h     = gelu(lnbuf @ w_fc + b_fc)       [gemm<2>]  (8192x1024)@(1024x4096)
//   out   = h @ w_fc2 + b_fc2 + out         [gemm<1>]  (in-place residual: safe,
//                                            each element read+written by same thread)
//
// Workspace layout (needs 192 MB):
//   [0,32MB)    lnbuf
//   [32,160MB)  big: qkv (96MB) then reused for h (128MB)
//   [160,192MB) ybuf (attention output, [B,T,C] layout)

#define M_ROWS 8192
#define T_SEQ 2048
#define N_EMB 1024
#define N_HEADS 16
#define HEAD_D 64

__device__ __forceinline__ float gelu_tanh(float v) {
    // tanh-approx GELU, matches jax.nn.gelu(approximate=True)
    float u = 0.7978845608028654f * (v + 0.044715f * v * v * v);
    float e = __expf(2.0f * u);            // tanh(u) = 1 - 2/(e^{2u}+1)
    float t = 1.0f - 2.0f / (e + 1.0f);
    return 0.5f * v * (1.0f + t);
}

// ---------------------------------------------------------------- LayerNorm
// One block per row of 1024. 256 threads, one float4 each.
__launch_bounds__(256)
__global__ void ln_kernel(const float* __restrict__ x, const float* __restrict__ g,
                          const float* __restrict__ b, float* __restrict__ y) {
    int row = blockIdx.x;
    int tid = threadIdx.x;
    const float* xr = x + (size_t)row * N_EMB;
    float4 v = *(const float4*)(xr + tid * 4);
    float s  = v.x + v.y + v.z + v.w;
    float sq = v.x * v.x + v.y * v.y + v.z * v.z + v.w * v.w;
    #pragma unroll
    for (int off = 32; off > 0; off >>= 1) {
        s  += __shfl_down(s, off);
        sq += __shfl_down(sq, off);
    }
    __shared__ float ws_[4], wq_[4];
    __shared__ float mean_s, rstd_s;
    int lane = tid & 63, wid = tid >> 6;
    if (lane == 0) { ws_[wid] = s; wq_[wid] = sq; }
    __syncthreads();
    if (tid == 0) {
        float st = ws_[0] + ws_[1] + ws_[2] + ws_[3];
        float qt = wq_[0] + wq_[1] + wq_[2] + wq_[3];
        float mu = st * (1.0f / N_EMB);
        float var = qt * (1.0f / N_EMB) - mu * mu;
        mean_s = mu;
        rstd_s = rsqrtf(var + 1e-5f);
    }
    __syncthreads();
    float mu = mean_s, r = rstd_s;
    float4 gv = *(const float4*)(g + tid * 4);
    float4 bv = *(const float4*)(b + tid * 4);
    float4 o;
    o.x = (v.x - mu) * r * gv.x + bv.x;
    o.y = (v.y - mu) * r * gv.y + bv.y;
    o.z = (v.z - mu) * r * gv.z + bv.z;
    o.w = (v.w - mu) * r * gv.w + bv.w;
    *(float4*)(y + (size_t)row * N_EMB + tid * 4) = o;
}

// ---------------------------------------------------------------- GEMM fp32
// C[M,N] = A[M,K] @ B[K,N] + bias (+ res | gelu).  128x128 tile, BK=16,
// 256 threads, 8x8 micro-tile. A staged transposed in LDS. Pad=4 keeps
// ds_read_b128 16B-aligned (stride 132 floats = 528B, multiple of 16).
// EPI: 0 = bias only, 1 = bias + residual, 2 = bias + gelu
template <int EPI>
__launch_bounds__(256)
__global__ void gemm_kernel(const float* __restrict__ A, const float* __restrict__ B,
                            const float* __restrict__ bias, const float* __restrict__ res,
                            float* __restrict__ C, int K, int N) {
    __shared__ float As[16][132];
    __shared__ float Bs[16][132];
    int tid = threadIdx.x;
    int tx = tid & 15, ty = tid >> 4;
    int m0 = blockIdx.y * 128, n0 = blockIdx.x * 128;
    int arow = tid >> 2, ac4 = tid & 3;
    int brow = tid >> 5, bc4 = tid & 31;
    float acc[8][8] = {};

    for (int k0 = 0; k0 < K; k0 += 16) {
        #pragma unroll
        for (int r = 0; r < 2; r++) {
            int row = r * 64 + arow;
            float4 a = *(const float4*)(A + (size_t)(m0 + row) * K + k0 + ac4 * 4);
            As[ac4 * 4 + 0][row] = a.x;
            As[ac4 * 4 + 1][row] = a.y;
            As[ac4 * 4 + 2][row] = a.z;
            As[ac4 * 4 + 3][row] = a.w;
        }
        #pragma unroll
        for (int r = 0; r < 2; r++) {
            int row = r * 8 + brow;
            *(float4*)(&Bs[row][bc4 * 4]) =
                *(const float4*)(B + (size_t)(k0 + row) * N + n0 + bc4 * 4);
        }
        __syncthreads();
        #pragma unroll
        for (int kk = 0; kk < 16; kk++) {
            float4 a0 = *(const float4*)&As[kk][ty * 8];
            float4 a1 = *(const float4*)&As[kk][ty * 8 + 4];
            float4 b0 = *(const float4*)&Bs[kk][tx * 8];
            float4 b1 = *(const float4*)&Bs[kk][tx * 8 + 4];
            float av[8] = {a0.x, a0.y, a0.z, a0.w, a1.x, a1.y, a1.z, a1.w};
            float bv[8] = {b0.x, b0.y, b0.z, b0.w, b1.x, b1.y, b1.z, b1.w};
            #pragma unroll
            for (int i = 0; i < 8; i++)
                #pragma unroll
                for (int j = 0; j < 8; j++)
                    acc[i][j] = fmaf(av[i], bv[j], acc[i][j]);
        }
        __syncthreads();
    }

    #pragma unroll
    for (int i = 0; i < 8; i++) {
        size_t row = m0 + ty * 8 + i;
        size_t base = row * (size_t)N + n0 + tx * 8;
        #pragma unroll
        for (int j4 = 0; j4 < 8; j4 += 4) {
            float4 bb = *(const float4*)(bias + n0 + tx * 8 + j4);
            float4 v;
            v.x = acc[i][j4 + 0] + bb.x;
            v.y = acc[i][j4 + 1] + bb.y;
            v.z = acc[i][j4 + 2] + bb.z;
            v.w = acc[i][j4 + 3] + bb.w;
            if (EPI == 1) {
                float4 r = *(const float4*)(res + base + j4);
                v.x += r.x; v.y += r.y; v.z += r.z; v.w += r.w;
            }
            if (EPI == 2) {
                v.x = gelu_tanh(v.x); v.y = gelu_tanh(v.y);
                v.z = gelu_tanh(v.z); v.w = gelu_tanh(v.w);
            }
            *(float4*)(C + base + j4) = v;
        }
    }
}

// ---------------------------------------------------------------- Flash attention
// qkv: [B,T,3C]; Q at col 0, K at col 1024, V at col 2048; head h uses cols h*64..h*64+63.
// Block = (qt, bh): 64-row Q tile for one (batch,head). 256 threads (16x16),
// 4x4 micro-tiles. Online softmax. Causal: only k-tiles jt <= qt; diagonal masked.
__launch_bounds__(256)
__global__ void flash_kernel(const float* __restrict__ qkv, float* __restrict__ y) {
    __shared__ float Qt[64][68];   // [d][i], pre-scaled by 1/sqrt(D)
    __shared__ float Kt[64][68];   // [d][j]
    __shared__ float Vs[64][68];   // [j][c]
    __shared__ float Ps[64][68];   // [j][i]  (P transposed -> A-operand order for PV)
    __shared__ float red[64][17];
    __shared__ float mrow[64], lrow[64], arow[64];

    int tid = threadIdx.x;
    int tx = tid & 15, ty = tid >> 4;
    int qt = blockIdx.x, bh = blockIdx.y;
    int b = bh >> 4, h = bh & 15;
    int q0 = qt * 64;
    const float* qbase = qkv + (size_t)b * T_SEQ * (3 * N_EMB) + h * HEAD_D;
    const float* kbase = qbase + N_EMB;
    const float* vbase = qbase + 2 * N_EMB;

    // Load + scale Q tile, transposed.
    #pragma unroll
    for (int r = 0; r < 4; r++) {
        int i = r * 16 + (tid >> 4);
        int d = (tid & 15) * 4;
        float4 q = *(const float4*)(qbase + (size_t)(q0 + i) * (3 * N_EMB) + d);
        Qt[d + 0][i] = q.x * 0.125f;
        Qt[d + 1][i] = q.y * 0.125f;
        Qt[d + 2][i] = q.z * 0.125f;
        Qt[d + 3][i] = q.w * 0.125f;
    }
    if (tid < 64) { mrow[tid] = -INFINITY; lrow[tid] = 0.0f; }
    float o[4][4] = {};

    for (int jt = 0; jt <= qt; jt++) {
        __syncthreads();   // protects Kt/Vs overwrite vs previous PV reads
        int j0 = jt * 64;
        #pragma unroll
        for (int r = 0; r < 4; r++) {
            int j = r * 16 + (tid >> 4);
            int d = (tid & 15) * 4;
            float4 kv = *(const float4*)(kbase + (size_t)(j0 + j) * (3 * N_EMB) + d);
            Kt[d + 0][j] = kv.x;
            Kt[d + 1][j] = kv.y;
            Kt[d + 2][j] = kv.z;
            Kt[d + 3][j] = kv.w;
            float4 vv = *(const float4*)(vbase + (size_t)(j0 + j) * (3 * N_EMB) + d);
            *(float4*)&Vs[j][d] = vv;
        }
        __syncthreads();

        // S = (Q/sqrt(D)) K^T, 4x4 per thread
        float s[4][4] = {};
        #pragma unroll 8
        for (int d = 0; d < 64; d++) {
            float4 qa = *(const float4*)&Qt[d][ty * 4];
            float4 kb = *(const float4*)&Kt[d][tx * 4];
            float qv[4] = {qa.x, qa.y, qa.z, qa.w};
            float kv[4] = {kb.x, kb.y, kb.z, kb.w};
            #pragma unroll
            for (int i = 0; i < 4; i++)
                #pragma unroll
                for (int j = 0; j < 4; j++)
                    s[i][j] = fmaf(qv[i], kv[j], s[i][j]);
        }
        if (jt == qt) {
            #pragma unroll
            for (int i = 0; i < 4; i++)
                #pragma unroll
                for (int j = 0; j < 4; j++)
                    if (tx * 4 + j > ty * 4 + i) s[i][j] = -1e30f;
        }

        // row max
        #pragma unroll
        for (int i = 0; i < 4; i++) {
            float rm = fmaxf(fmaxf(s[i][0], s[i][1]), fmaxf(s[i][2], s[i][3]));
            red[ty * 4 + i][tx] = rm;
        }
        __syncthreads();
        if (tid < 64) {
            float mold = mrow[tid], mx = mold;
            #pragma unroll
            for (int t = 0; t < 16; t++) mx = fmaxf(mx, red[tid][t]);
            mrow[tid] = mx;
            arow[tid] = __expf(mold - mx);   // first tile: exp(-inf - finite) = 0
        }
        __syncthreads();

        // P = exp(S - m), write transposed; partial row sums
        #pragma unroll
        for (int i = 0; i < 4; i++) {
            float mi = mrow[ty * 4 + i];
            float rs = 0.0f;
            #pragma unroll
            for (int j = 0; j < 4; j++) {
                float p = __expf(s[i][j] - mi);
                Ps[tx * 4 + j][ty * 4 + i] = p;
                rs += p;
            }
            red[ty * 4 + i][tx] = rs;
        }
        __syncthreads();
        if (tid < 64) {
            float ss = 0.0f;
            #pragma unroll
            for (int t = 0; t < 16; t++) ss += red[tid][t];
            lrow[tid] = lrow[tid] * arow[tid] + ss;
        }

        // O = O*alpha + P V
        float al[4];
        #pragma unroll
        for (int i = 0; i < 4; i++) al[i] = arow[ty * 4 + i];
        #pragma unroll
        for (int i = 0; i < 4; i++)
            #pragma unroll
            for (int c = 0; c < 4; c++) o[i][c] *= al[i];
        #pragma unroll 8
        for (int j = 0; j < 64; j++) {
            float4 pa = *(const float4*)&Ps[j][ty * 4];
            float4 vb = *(const float4*)&Vs[j][tx * 4];
            float pv[4] = {pa.x, pa.y, pa.z, pa.w};
            float vv[4] = {vb.x, vb.y, vb.z, vb.w};
            #pragma unroll
            for (int i = 0; i < 4; i++)
                #pragma unroll
                for (int c = 0; c < 4; c++)
                    o[i][c] = fmaf(pv[i], vv[c], o[i][c]);
        }
    }
    __syncthreads();   // lrow final

    #pragma unroll
    for (int i = 0; i < 4; i++) {
        float linv = 1.0f / lrow[ty * 4 + i];
        float4 ov;
        ov.x = o[i][0] * linv;
        ov.y = o[i][1] * linv;
        ov.z = o[i][2] * linv;
        ov.w = o[i][3] * linv;
        *(float4*)(y + ((size_t)b * T_SEQ + q0 + ty * 4 + i) * N_EMB + h * HEAD_D + tx * 4) = ov;
    }
}

// ---------------------------------------------------------------- launch
extern "C" void kernel_launch(void* const* d_in, const int* in_sizes, int n_in,
                              void* d_out, int out_size, void* d_ws, size_t ws_size,
                              hipStream_t stream) {
    const float* x      = (const float*)d_in[0];
    const float* ln1_g  = (const float*)d_in[1];
    const float* ln1_b  = (const float*)d_in[2];
    const float* w_attn = (const float*)d_in[3];
    const float* b_attn = (const float*)d_in[4];
    const float* w_proj = (const float*)d_in[5];
    const float* b_proj = (const float*)d_in[6];
    const float* ln2_g  = (const float*)d_in[7];
    const float* ln2_b  = (const float*)d_in[8];
    const float* w_fc   = (const float*)d_in[9];
    const float* b_fc   = (const float*)d_in[10];
    const float* w_fc2  = (const float*)d_in[11];
    const float* b_fc2  = (const float*)d_in[12];
    float* out = (float*)d_out;

    char* ws = (char*)d_ws;
    float* lnbuf = (float*)ws;                              // 32 MB
    float* big   = (float*)(ws + (size_t)32 * 1024 * 1024); // 128 MB (qkv, then h)
    float* ybuf  = (float*)(ws + (size_t)160 * 1024 * 1024);// 32 MB

    // 1. LN1
    ln_kernel<<<M_ROWS, 256, 0, stream>>>(x, ln1_g, ln1_b, lnbuf);
    // 2. QKV = lnbuf @ w_attn + b_attn        [8192,1024]x[1024,3072]
    gemm_kernel<0><<<dim3(3072 / 128, M_ROWS / 128), 256, 0, stream>>>(
        lnbuf, w_attn, b_attn, nullptr, big, 1024, 3072);
    // 3. Flash attention
    flash_kernel<<<dim3(T_SEQ / 64, 4 * N_HEADS), 256, 0, stream>>>(big, ybuf);
    // 4. out = ybuf @ w_proj + b_proj + x
    gemm_kernel<1><<<dim3(1024 / 128, M_ROWS / 128), 256, 0, stream>>>(
        ybuf, w_proj, b_proj, x, out, 1024, 1024);
    // 5. LN2
    ln_kernel<<<M_ROWS, 256, 0, stream>>>(out, ln2_g, ln2_b, lnbuf);
    // 6. h = gelu(lnbuf @ w_fc + b_fc)        [8192,1024]x[1024,4096]
    gemm_kernel<2><<<dim3(4096 / 128, M_ROWS / 128), 256, 0, stream>>>(
        lnbuf, w_fc, b_fc, nullptr, big, 1024, 4096);
    // 7. out = big @ w_fc2 + b_fc2 + out      [8192,4096]x[4096,1024], in-place residual
    gemm_kernel<1><<<dim3(1024 / 128, M_ROWS / 128), 256, 0, stream>>>(
        big, w_fc2, b_fc2, out, out, 4096, 1024);
}

// Round 2
// 1615.454 us; speedup vs baseline: 2.2116x; 2.2116x over previous
//
#include <hip/hip_runtime.h>
#include <math.h>

// Round 2: fp16-MFMA GEMMs (m97-style), flash attention math unchanged (fp32).
// Pipeline:
//   wT_*  = transpose+f16(w_*)              [wconv_kernel x4]
//   lnbuf = LN(x, ln1) -> f16               [ln_kernel]
//   qkv   = lnbuf @ wT_attn + b_attn (f32)  [gemm_f16<0>]
//   ybuf  = flash(qkv) -> f16               [flash_kernel, fp32 math]
//   out   = ybuf @ wT_proj + b_proj + x     [gemm_f16<1>]
//   lnbuf = LN(out, ln2) -> f16             [ln_kernel]
//   h     = gelu(lnbuf @ wT_fc + b_fc) f16  [gemm_f16<2>]  (h overlays dead qkv)
//   out   = h @ wT_fc2 + b_fc2 + out        [gemm_f16<1>]  (in-place residual)
//
// ws layout: [0,16M) lnbuf f16 | [16,112M) qkv f32 / h f16 | [112,128M) ybuf f16
//            [128,154M) wT f16 (attn 6M, proj 2M, fc 8M, fc2 8M)

#define M_ROWS 8192
#define T_SEQ 2048
#define N_EMB 1024
#define N_HEADS 16
#define HEAD_D 64

typedef _Float16 f16;
typedef __attribute__((ext_vector_type(8))) _Float16 f16x8;
typedef __attribute__((ext_vector_type(4))) _Float16 f16x4;
typedef __attribute__((ext_vector_type(4))) float f32x4;

__device__ __forceinline__ void async16(void* lds, const void* g) {
    __builtin_amdgcn_global_load_lds(
        (const __attribute__((address_space(1))) unsigned int*)g,
        (__attribute__((address_space(3))) unsigned int*)lds, 16, 0, 0);
}

__device__ __forceinline__ float gelu_tanh(float v) {
    float u = 0.7978845608028654f * (v + 0.044715f * v * v * v);
    float e = __expf(2.0f * u);
    float t = 1.0f - 2.0f / (e + 1.0f);
    return 0.5f * v * (1.0f + t);
}

// ---------------------------------------------------------------- weight convert
// W[K,N] f32 -> WT[N,K] f16. 32x32 tiles, coalesced both sides.
__launch_bounds__(256)
__global__ void wconv_kernel(const float* __restrict__ W, f16* __restrict__ WT,
                             int K, int N) {
    __shared__ float t[32][33];
    int tx = threadIdx.x & 31, ty = threadIdx.x >> 5;   // 32 x 8
    int n0 = blockIdx.x * 32, k0 = blockIdx.y * 32;
    #pragma unroll
    for (int r = 0; r < 4; r++)
        t[ty * 4 + r][tx] = W[(size_t)(k0 + ty * 4 + r) * N + n0 + tx];
    __syncthreads();
    #pragma unroll
    for (int r = 0; r < 4; r++)
        WT[(size_t)(n0 + ty * 4 + r) * K + k0 + tx] = (f16)t[tx][ty * 4 + r];
}

// ---------------------------------------------------------------- LayerNorm -> f16
__launch_bounds__(256)
__global__ void ln_kernel(const float* __restrict__ x, const float* __restrict__ g,
                          const float* __restrict__ b, f16* __restrict__ y) {
    int row = blockIdx.x;
    int tid = threadIdx.x;
    const float* xr = x + (size_t)row * N_EMB;
    float4 v = *(const float4*)(xr + tid * 4);
    float s  = v.x + v.y + v.z + v.w;
    float sq = v.x * v.x + v.y * v.y + v.z * v.z + v.w * v.w;
    #pragma unroll
    for (int off = 32; off > 0; off >>= 1) {
        s  += __shfl_down(s, off);
        sq += __shfl_down(sq, off);
    }
    __shared__ float ws_[4], wq_[4];
    __shared__ float mean_s, rstd_s;
    int lane = tid & 63, wid = tid >> 6;
    if (lane == 0) { ws_[wid] = s; wq_[wid] = sq; }
    __syncthreads();
    if (tid == 0) {
        float st = ws_[0] + ws_[1] + ws_[2] + ws_[3];
        float qt = wq_[0] + wq_[1] + wq_[2] + wq_[3];
        float mu = st * (1.0f / N_EMB);
        float var = qt * (1.0f / N_EMB) - mu * mu;
        mean_s = mu;
        rstd_s = rsqrtf(var + 1e-5f);
    }
    __syncthreads();
    float mu = mean_s, r = rstd_s;
    float4 gv = *(const float4*)(g + tid * 4);
    float4 bv = *(const float4*)(b + tid * 4);
    f16x4 o;
    o.x = (f16)((v.x - mu) * r * gv.x + bv.x);
    o.y = (f16)((v.y - mu) * r * gv.y + bv.y);
    o.z = (f16)((v.z - mu) * r * gv.z + bv.z);
    o.w = (f16)((v.w - mu) * r * gv.w + bv.w);
    *(f16x4*)(y + (size_t)row * N_EMB + tid * 4) = o;
}

// ---------------------------------------------------------------- GEMM f16 MFMA
// C[M,N] = A[M,K](f16) @ Bt[N,K]^T(f16) + bias. m97 structure: 128x128 tile,
// BK=32, 256 threads = 4 waves (2x2 of 64x64), 4x4 grid of 16x16x32 MFMA.
// global_load_lds width=16 staging, single LDS buffer, 2 barriers per k-step.
// EPI: 0 = f32 store, 1 = f32 store + f32 residual, 2 = gelu -> f16 store
template <int EPI>
__launch_bounds__(256)
__global__ void gemm_f16(const f16* __restrict__ A, const f16* __restrict__ Bt,
                         const float* __restrict__ bias, const float* __restrict__ res,
                         float* __restrict__ Cf, f16* __restrict__ Ch, int K, int N) {
    __shared__ f16 As[128 * 32];
    __shared__ f16 Bs[128 * 32];
    int tid = threadIdx.x;
    int lane = tid & 63, wave = tid >> 6;
    int wr = wave >> 1, wc = wave & 1;
    int quad = lane >> 4, l16 = lane & 15;
    int m0 = blockIdx.y * 128, n0 = blockIdx.x * 128;

    f32x4 acc[4][4] = {};

    for (int k0 = 0; k0 < K; k0 += 32) {
        // stage A,B tiles (128x32 f16 = 8KB each): 512 16B-segments per tile,
        // LDS dest = contiguous in (inst,wave,lane) order as required.
        #pragma unroll
        for (int i = 0; i < 2; i++) {
            int L = i * 256 + tid;
            int row = L >> 2, seg = L & 3;
            async16((char*)As + (size_t)L * 16,
                    A + (size_t)(m0 + row) * K + k0 + seg * 8);
        }
        #pragma unroll
        for (int i = 0; i < 2; i++) {
            int L = i * 256 + tid;
            int row = L >> 2, seg = L & 3;
            async16((char*)Bs + (size_t)L * 16,
                    Bt + (size_t)(n0 + row) * K + k0 + seg * 8);
        }
        __syncthreads();   // includes vmcnt(0) drain of global_load_lds

        f16x8 af[4], bf[4];
        #pragma unroll
        for (int i = 0; i < 4; i++)
            af[i] = *(const f16x8*)&As[(wr * 64 + i * 16 + l16) * 32 + quad * 8];
        #pragma unroll
        for (int j = 0; j < 4; j++)
            bf[j] = *(const f16x8*)&Bs[(wc * 64 + j * 16 + l16) * 32 + quad * 8];
        #pragma unroll
        for (int i = 0; i < 4; i++)
            #pragma unroll
            for (int j = 0; j < 4; j++)
                acc[i][j] = __builtin_amdgcn_mfma_f32_16x16x32_f16(
                    af[i], bf[j], acc[i][j], 0, 0, 0);
        __syncthreads();
    }

    // epilogue: C/D layout col=lane&15, row=quad*4+r
    #pragma unroll
    for (int i = 0; i < 4; i++) {
        int row0 = m0 + wr * 64 + i * 16 + quad * 4;
        #pragma unroll
        for (int j = 0; j < 4; j++) {
            int col = n0 + wc * 64 + j * 16 + l16;
            float bb = bias[col];
            #pragma unroll
            for (int r = 0; r < 4; r++) {
                size_t idx = (size_t)(row0 + r) * N + col;
                float v = acc[i][j][r] + bb;
                if (EPI == 1) v += res[idx];
                if (EPI == 2) Ch[idx] = (f16)gelu_tanh(v);
                else          Cf[idx] = v;
            }
        }
    }
}

// ---------------------------------------------------------------- Flash attention
// Math identical to round 1 (fp32); only the output store is f16 now.
__launch_bounds__(256)
__global__ void flash_kernel(const float* __restrict__ qkv, f16* __restrict__ y) {
    __shared__ float Qt[64][68];
    __shared__ float Kt[64][68];
    __shared__ float Vs[64][68];
    __shared__ float Ps[64][68];
    __shared__ float red[64][17];
    __shared__ float mrow[64], lrow[64], arow[64];

    int tid = threadIdx.x;
    int tx = tid & 15, ty = tid >> 4;
    int qt = blockIdx.x, bh = blockIdx.y;
    int b = bh >> 4, h = bh & 15;
    int q0 = qt * 64;
    const float* qbase = qkv + (size_t)b * T_SEQ * (3 * N_EMB) + h * HEAD_D;
    const float* kbase = qbase + N_EMB;
    const float* vbase = qbase + 2 * N_EMB;

    #pragma unroll
    for (int r = 0; r < 4; r++) {
        int i = r * 16 + (tid >> 4);
        int d = (tid & 15) * 4;
        float4 q = *(const float4*)(qbase + (size_t)(q0 + i) * (3 * N_EMB) + d);
        Qt[d + 0][i] = q.x * 0.125f;
        Qt[d + 1][i] = q.y * 0.125f;
        Qt[d + 2][i] = q.z * 0.125f;
        Qt[d + 3][i] = q.w * 0.125f;
    }
    if (tid < 64) { mrow[tid] = -INFINITY; lrow[tid] = 0.0f; }
    float o[4][4] = {};

    for (int jt = 0; jt <= qt; jt++) {
        __syncthreads();
        int j0 = jt * 64;
        #pragma unroll
        for (int r = 0; r < 4; r++) {
            int j = r * 16 + (tid >> 4);
            int d = (tid & 15) * 4;
            float4 kv = *(const float4*)(kbase + (size_t)(j0 + j) * (3 * N_EMB) + d);
            Kt[d + 0][j] = kv.x;
            Kt[d + 1][j] = kv.y;
            Kt[d + 2][j] = kv.z;
            Kt[d + 3][j] = kv.w;
            float4 vv = *(const float4*)(vbase + (size_t)(j0 + j) * (3 * N_EMB) + d);
            *(float4*)&Vs[j][d] = vv;
        }
        __syncthreads();

        float s[4][4] = {};
        #pragma unroll 8
        for (int d = 0; d < 64; d++) {
            float4 qa = *(const float4*)&Qt[d][ty * 4];
            float4 kb = *(const float4*)&Kt[d][tx * 4];
            float qv[4] = {qa.x, qa.y, qa.z, qa.w};
            float kv[4] = {kb.x, kb.y, kb.z, kb.w};
            #pragma unroll
            for (int i = 0; i < 4; i++)
                #pragma unroll
                for (int j = 0; j < 4; j++)
                    s[i][j] = fmaf(qv[i], kv[j], s[i][j]);
        }
        if (jt == qt) {
            #pragma unroll
            for (int i = 0; i < 4; i++)
                #pragma unroll
                for (int j = 0; j < 4; j++)
                    if (tx * 4 + j > ty * 4 + i) s[i][j] = -1e30f;
        }

        #pragma unroll
        for (int i = 0; i < 4; i++) {
            float rm = fmaxf(fmaxf(s[i][0], s[i][1]), fmaxf(s[i][2], s[i][3]));
            red[ty * 4 + i][tx] = rm;
        }
        __syncthreads();
        if (tid < 64) {
            float mold = mrow[tid], mx = mold;
            #pragma unroll
            for (int t = 0; t < 16; t++) mx = fmaxf(mx, red[tid][t]);
            mrow[tid] = mx;
            arow[tid] = __expf(mold - mx);
        }
        __syncthreads();

        #pragma unroll
        for (int i = 0; i < 4; i++) {
            float mi = mrow[ty * 4 + i];
            float rs = 0.0f;
            #pragma unroll
            for (int j = 0; j < 4; j++) {
                float p = __expf(s[i][j] - mi);
                Ps[tx * 4 + j][ty * 4 + i] = p;
                rs += p;
            }
            red[ty * 4 + i][tx] = rs;
        }
        __syncthreads();
        if (tid < 64) {
            float ss = 0.0f;
            #pragma unroll
            for (int t = 0; t < 16; t++) ss += red[tid][t];
            lrow[tid] = lrow[tid] * arow[tid] + ss;
        }

        float al[4];
        #pragma unroll
        for (int i = 0; i < 4; i++) al[i] = arow[ty * 4 + i];
        #pragma unroll
        for (int i = 0; i < 4; i++)
            #pragma unroll
            for (int c = 0; c < 4; c++) o[i][c] *= al[i];
        #pragma unroll 8
        for (int j = 0; j < 64; j++) {
            float4 pa = *(const float4*)&Ps[j][ty * 4];
            float4 vb = *(const float4*)&Vs[j][tx * 4];
            float pv[4] = {pa.x, pa.y, pa.z, pa.w};
            float vv[4] = {vb.x, vb.y, vb.z, vb.w};
            #pragma unroll
            for (int i = 0; i < 4; i++)
                #pragma unroll
                for (int c = 0; c < 4; c++)
                    o[i][c] = fmaf(pv[i], vv[c], o[i][c]);
        }
    }
    __syncthreads();

    #pragma unroll
    for (int i = 0; i < 4; i++) {
        float linv = 1.0f / lrow[ty * 4 + i];
        f16x4 ov;
        ov.x = (f16)(o[i][0] * linv);
        ov.y = (f16)(o[i][1] * linv);
        ov.z = (f16)(o[i][2] * linv);
        ov.w = (f16)(o[i][3] * linv);
        *(f16x4*)(y + ((size_t)b * T_SEQ + q0 + ty * 4 + i) * N_EMB + h * HEAD_D + tx * 4) = ov;
    }
}

// ---------------------------------------------------------------- launch
extern "C" void kernel_launch(void* const* d_in, const int* in_sizes, int n_in,
                              void* d_out, int out_size, void* d_ws, size_t ws_size,
                              hipStream_t stream) {
    const float* x      = (const float*)d_in[0];
    const float* ln1_g  = (const float*)d_in[1];
    const float* ln1_b  = (const float*)d_in[2];
    const float* w_attn = (const float*)d_in[3];
    const float* b_attn = (const float*)d_in[4];
    const float* w_proj = (const float*)d_in[5];
    const float* b_proj = (const float*)d_in[6];
    const float* ln2_g  = (const float*)d_in[7];
    const float* ln2_b  = (const float*)d_in[8];
    const float* w_fc   = (const float*)d_in[9];
    const float* b_fc   = (const float*)d_in[10];
    const float* w_fc2  = (const float*)d_in[11];
    const float* b_fc2  = (const float*)d_in[12];
    float* out = (float*)d_out;

    const size_t MB = 1024 * 1024;
    char* ws = (char*)d_ws;
    f16*   lnbuf = (f16*)ws;                        // 16 MB
    float* qkv   = (float*)(ws + 16 * MB);          // 96 MB
    f16*   h     = (f16*)(ws + 16 * MB);            // 64 MB (overlays dead qkv)
    f16*   ybuf  = (f16*)(ws + 112 * MB);           // 16 MB
    f16*   wT    = (f16*)(ws + 128 * MB);           // 26 MB total
    f16* wT_attn = wT;
    f16* wT_proj = wT_attn + (size_t)3072 * 1024;
    f16* wT_fc   = wT_proj + (size_t)1024 * 1024;
    f16* wT_fc2  = wT_fc   + (size_t)1024 * 4096;

    // 0. weight transpose+convert (f32 [K,N] -> f16 [N,K])
    wconv_kernel<<<dim3(3072 / 32, 1024 / 32), 256, 0, stream>>>(w_attn, wT_attn, 1024, 3072);
    wconv_kernel<<<dim3(1024 / 32, 1024 / 32), 256, 0, stream>>>(w_proj, wT_proj, 1024, 1024);
    wconv_kernel<<<dim3(4096 / 32, 1024 / 32), 256, 0, stream>>>(w_fc,   wT_fc,   1024, 4096);
    wconv_kernel<<<dim3(1024 / 32, 4096 / 32), 256, 0, stream>>>(w_fc2,  wT_fc2,  4096, 1024);

    // 1. LN1 -> f16
    ln_kernel<<<M_ROWS, 256, 0, stream>>>(x, ln1_g, ln1_b, lnbuf);
    // 2. qkv = lnbuf @ w_attn + b_attn (f32 out)
    gemm_f16<0><<<dim3(3072 / 128, M_ROWS / 128), 256, 0, stream>>>(
        lnbuf, wT_attn, b_attn, nullptr, qkv, nullptr, 1024, 3072);
    // 3. flash attention (fp32 math) -> f16
    flash_kernel<<<dim3(T_SEQ / 64, 4 * N_HEADS), 256, 0, stream>>>(qkv, ybuf);
    // 4. out = ybuf @ w_proj + b_proj + x
    gemm_f16<1><<<dim3(1024 / 128, M_ROWS / 128), 256, 0, stream>>>(
        ybuf, wT_proj, b_proj, x, out, nullptr, 1024, 1024);
    // 5. LN2 -> f16
    ln_kernel<<<M_ROWS, 256, 0, stream>>>(out, ln2_g, ln2_b, lnbuf);
    // 6. h = gelu(lnbuf @ w_fc + b_fc) -> f16
    gemm_f16<2><<<dim3(4096 / 128, M_ROWS / 128), 256, 0, stream>>>(
        lnbuf, wT_fc, b_fc, nullptr, nullptr, h, 1024, 4096);
    // 7. out = h @ w_fc2 + b_fc2 + out (in-place residual, same-thread RMW)
    gemm_f16<1><<<dim3(1024 / 128, M_ROWS / 128), 256, 0, stream>>>(
        h, wT_fc2, b_fc2, out, out, nullptr, 4096, 1024);
}

// Round 3
// 609.553 us; speedup vs baseline: 5.8613x; 2.6502x over previous
//
#include <hip/hip_runtime.h>
#include <math.h>

// Round 3: MFMA flash attention (f16 in, f32 softmax/acc). GEMMs unchanged
// from round 2 except the QKV epilogue (EPI=3) which now emits:
//   Q,K -> f16 buffer qk[M][2048]  (cols 0..1023 Q, 1024..2047 K)
//   V   -> f16 buffer vT[b][h][64 d][2048 t]   (transposed for PV B-frags)
//
// Pipeline:
//   wT_*  = transpose+f16(w_*)                   [wconv x4]
//   lnbuf = LN(x, ln1) -> f16                    [ln_kernel]
//   qk,vT = lnbuf @ wT_attn + b_attn             [gemm_f16<3>]
//   ybuf  = mfma_flash(qk, vT) -> f16            [flash_kernel]
//   out   = ybuf @ wT_proj + b_proj + x          [gemm_f16<1>]
//   lnbuf = LN(out, ln2) -> f16                  [ln_kernel]
//   h     = gelu(lnbuf @ wT_fc + b_fc) -> f16    [gemm_f16<2>]
//   out   = h @ wT_fc2 + b_fc2 + out             [gemm_f16<1>]
//
// ws: [0,16M) lnbuf | [16,48M) qk | [48,64M) vT | [64,80M) ybuf
//     [80,144M) h | [144,170M) wT

#define M_ROWS 8192
#define T_SEQ 2048
#define N_EMB 1024
#define N_HEADS 16
#define HEAD_D 64

typedef _Float16 f16;
typedef __attribute__((ext_vector_type(8))) _Float16 f16x8;
typedef __attribute__((ext_vector_type(4))) _Float16 f16x4;
typedef __attribute__((ext_vector_type(4))) float f32x4;

__device__ __forceinline__ void async16(void* lds, const void* g) {
    __builtin_amdgcn_global_load_lds(
        (const __attribute__((address_space(1))) unsigned int*)g,
        (__attribute__((address_space(3))) unsigned int*)lds, 16, 0, 0);
}

__device__ __forceinline__ float gelu_tanh(float v) {
    float u = 0.7978845608028654f * (v + 0.044715f * v * v * v);
    float e = __expf(2.0f * u);
    float t = 1.0f - 2.0f / (e + 1.0f);
    return 0.5f * v * (1.0f + t);
}

// ---------------------------------------------------------------- weight convert
__launch_bounds__(256)
__global__ void wconv_kernel(const float* __restrict__ W, f16* __restrict__ WT,
                             int K, int N) {
    __shared__ float t[32][33];
    int tx = threadIdx.x & 31, ty = threadIdx.x >> 5;
    int n0 = blockIdx.x * 32, k0 = blockIdx.y * 32;
    #pragma unroll
    for (int r = 0; r < 4; r++)
        t[ty * 4 + r][tx] = W[(size_t)(k0 + ty * 4 + r) * N + n0 + tx];
    __syncthreads();
    #pragma unroll
    for (int r = 0; r < 4; r++)
        WT[(size_t)(n0 + ty * 4 + r) * K + k0 + tx] = (f16)t[tx][ty * 4 + r];
}

// ---------------------------------------------------------------- LayerNorm -> f16
__launch_bounds__(256)
__global__ void ln_kernel(const float* __restrict__ x, const float* __restrict__ g,
                          const float* __restrict__ b, f16* __restrict__ y) {
    int row = blockIdx.x;
    int tid = threadIdx.x;
    const float* xr = x + (size_t)row * N_EMB;
    float4 v = *(const float4*)(xr + tid * 4);
    float s  = v.x + v.y + v.z + v.w;
    float sq = v.x * v.x + v.y * v.y + v.z * v.z + v.w * v.w;
    #pragma unroll
    for (int off = 32; off > 0; off >>= 1) {
        s  += __shfl_down(s, off);
        sq += __shfl_down(sq, off);
    }
    __shared__ float ws_[4], wq_[4];
    __shared__ float mean_s, rstd_s;
    int lane = tid & 63, wid = tid >> 6;
    if (lane == 0) { ws_[wid] = s; wq_[wid] = sq; }
    __syncthreads();
    if (tid == 0) {
        float st = ws_[0] + ws_[1] + ws_[2] + ws_[3];
        float qt = wq_[0] + wq_[1] + wq_[2] + wq_[3];
        float mu = st * (1.0f / N_EMB);
        float var = qt * (1.0f / N_EMB) - mu * mu;
        mean_s = mu;
        rstd_s = rsqrtf(var + 1e-5f);
    }
    __syncthreads();
    float mu = mean_s, r = rstd_s;
    float4 gv = *(const float4*)(g + tid * 4);
    float4 bv = *(const float4*)(b + tid * 4);
    f16x4 o;
    o.x = (f16)((v.x - mu) * r * gv.x + bv.x);
    o.y = (f16)((v.y - mu) * r * gv.y + bv.y);
    o.z = (f16)((v.z - mu) * r * gv.z + bv.z);
    o.w = (f16)((v.w - mu) * r * gv.w + bv.w);
    *(f16x4*)(y + (size_t)row * N_EMB + tid * 4) = o;
}

// ---------------------------------------------------------------- GEMM f16 MFMA
// EPI: 0 f32 store | 1 f32 + residual | 2 gelu->f16 | 3 qkv split (Q,K->qk f16;
// V->vT f16 transposed)
template <int EPI>
__launch_bounds__(256)
__global__ void gemm_f16(const f16* __restrict__ A, const f16* __restrict__ Bt,
                         const float* __restrict__ bias, const float* __restrict__ res,
                         float* __restrict__ Cf, f16* __restrict__ Ch,
                         f16* __restrict__ vT, int K, int N) {
    __shared__ f16 As[128 * 32];
    __shared__ f16 Bs[128 * 32];
    int tid = threadIdx.x;
    int lane = tid & 63, wave = tid >> 6;
    int wr = wave >> 1, wc = wave & 1;
    int quad = lane >> 4, l16 = lane & 15;
    int m0 = blockIdx.y * 128, n0 = blockIdx.x * 128;

    f32x4 acc[4][4] = {};

    for (int k0 = 0; k0 < K; k0 += 32) {
        #pragma unroll
        for (int i = 0; i < 2; i++) {
            int L = i * 256 + tid;
            int row = L >> 2, seg = L & 3;
            async16((char*)As + (size_t)L * 16,
                    A + (size_t)(m0 + row) * K + k0 + seg * 8);
        }
        #pragma unroll
        for (int i = 0; i < 2; i++) {
            int L = i * 256 + tid;
            int row = L >> 2, seg = L & 3;
            async16((char*)Bs + (size_t)L * 16,
                    Bt + (size_t)(n0 + row) * K + k0 + seg * 8);
        }
        __syncthreads();

        f16x8 af[4], bf[4];
        #pragma unroll
        for (int i = 0; i < 4; i++)
            af[i] = *(const f16x8*)&As[(wr * 64 + i * 16 + l16) * 32 + quad * 8];
        #pragma unroll
        for (int j = 0; j < 4; j++)
            bf[j] = *(const f16x8*)&Bs[(wc * 64 + j * 16 + l16) * 32 + quad * 8];
        #pragma unroll
        for (int i = 0; i < 4; i++)
            #pragma unroll
            for (int j = 0; j < 4; j++)
                acc[i][j] = __builtin_amdgcn_mfma_f32_16x16x32_f16(
                    af[i], bf[j], acc[i][j], 0, 0, 0);
        __syncthreads();
    }

    #pragma unroll
    for (int i = 0; i < 4; i++) {
        int row0 = m0 + wr * 64 + i * 16 + quad * 4;
        #pragma unroll
        for (int j = 0; j < 4; j++) {
            int col = n0 + wc * 64 + j * 16 + l16;
            float bb = bias[col];
            if (EPI == 3) {
                if (n0 < 2048) {
                    #pragma unroll
                    for (int r = 0; r < 4; r++)
                        Ch[(size_t)(row0 + r) * 2048 + col] = (f16)(acc[i][j][r] + bb);
                } else {
                    int hh = (col - 2048) >> 6, dd = col & 63;
                    int bb_ = row0 >> 11, t0 = row0 & 2047;
                    f16x4 pk;
                    pk.x = (f16)(acc[i][j][0] + bb);
                    pk.y = (f16)(acc[i][j][1] + bb);
                    pk.z = (f16)(acc[i][j][2] + bb);
                    pk.w = (f16)(acc[i][j][3] + bb);
                    *(f16x4*)(vT + ((size_t)(bb_ * 16 + hh) * 64 + dd) * 2048 + t0) = pk;
                }
            } else {
                #pragma unroll
                for (int r = 0; r < 4; r++) {
                    size_t idx = (size_t)(row0 + r) * N + col;
                    float v = acc[i][j][r] + bb;
                    if (EPI == 1) v += res[idx];
                    if (EPI == 2) Ch[idx] = (f16)gelu_tanh(v);
                    else          Cf[idx] = v;
                }
            }
        }
    }
}

// ---------------------------------------------------------------- MFMA flash
// Block: 256 thr = 4 waves; 128 q-rows (wave w owns rows [w*32,w*32+32)),
// iterate 128-wide j-tiles (causal: jt <= qt). S^T = K.Q^T via MFMA (C-layout
// gives 4 consecutive j per lane -> b64 P-writes). PV: A=P (LDS), B=V^T (LDS).
// K/V staged by global_load_lds w=16 with XOR-8-group swizzle (conflict-free).
__launch_bounds__(256, 2)
__global__ void flash_kernel(const f16* __restrict__ qk, const f16* __restrict__ vT,
                             f16* __restrict__ y) {
    __shared__ __align__(16) char smem[67584];
    f16* Ks = (f16*)smem;                      // [128 j][8 groups of 8 d], swizzled
    f16* Vs = (f16*)(smem + 16384);            // [64 d][16 groups of 8 j], swizzled
    int tid = threadIdx.x;
    int lane = tid & 63, w = tid >> 6;
    int quad = lane >> 4, l16 = lane & 15;
    f16* Ps = (f16*)(smem + 32768 + w * 8704); // per-wave [32 q][136 j]

    int qt = 15 - blockIdx.x;                  // reversed: long blocks first
    int bh = blockIdx.y;
    int b = bh >> 4, h = bh & 15;
    int q0 = qt * 128;

    // Q B-frags (once): B[k=d][n=q], lane: q = l16, k = quad*8+t
    f16x8 qf[2][2];
    #pragma unroll
    for (int qn = 0; qn < 2; qn++) {
        int q = q0 + w * 32 + qn * 16 + l16;
        #pragma unroll
        for (int dblk = 0; dblk < 2; dblk++)
            qf[qn][dblk] = *(const f16x8*)(qk + (size_t)(b * T_SEQ + q) * 2048 +
                                           h * 64 + dblk * 32 + quad * 8);
    }

    float m_r[2] = {-INFINITY, -INFINITY};
    float l_r[2] = {0.0f, 0.0f};
    f32x4 Oacc[2][4] = {};
    const float scale = 0.125f;  // 1/sqrt(64)

    for (int jt = 0; jt <= qt; jt++) {
        int j0 = jt * 128;
        __syncthreads();
        // stage K tile: rows j (128), 8 groups/row, swizzle g' = g ^ (j&7)
        #pragma unroll
        for (int i = 0; i < 4; i++) {
            int L = i * 256 + tid;
            int j = L >> 3, g1 = L & 7;
            int g = g1 ^ (j & 7);
            async16((char*)Ks + (size_t)L * 16,
                    qk + (size_t)(b * T_SEQ + j0 + j) * 2048 + 1024 + h * 64 + g * 8);
        }
        // stage V^T tile: rows d (64), 16 groups/row, swizzle g' = g ^ (d&7)
        #pragma unroll
        for (int i = 0; i < 4; i++) {
            int L = i * 256 + tid;
            int d = L >> 4, g1 = L & 15;
            int g = (g1 & 8) | ((g1 ^ d) & 7);
            async16((char*)Vs + (size_t)L * 16,
                    vT + ((size_t)(bh) * 64 + d) * 2048 + j0 + g * 8);
        }
        __syncthreads();

        // S^T = K . Q^T : C-layout lane holds col q = l16, rows j = quad*4+r
        f32x4 S[8][2];
        #pragma unroll
        for (int jm = 0; jm < 8; jm++) {
            f16x8 kf[2];
            #pragma unroll
            for (int dblk = 0; dblk < 2; dblk++) {
                int j = jm * 16 + l16;
                int g = (dblk * 4 + quad) ^ (j & 7);
                kf[dblk] = *(const f16x8*)(Ks + (size_t)(j * 8 + g) * 8);
            }
            #pragma unroll
            for (int qn = 0; qn < 2; qn++) {
                f32x4 s = {};
                s = __builtin_amdgcn_mfma_f32_16x16x32_f16(kf[0], qf[qn][0], s, 0, 0, 0);
                s = __builtin_amdgcn_mfma_f32_16x16x32_f16(kf[1], qf[qn][1], s, 0, 0, 0);
                S[jm][qn] = s;
            }
        }

        if (jt == qt) {  // diagonal: mask j > q (tile-local indices)
            #pragma unroll
            for (int jm = 0; jm < 8; jm++)
                #pragma unroll
                for (int qn = 0; qn < 2; qn++)
                    #pragma unroll
                    for (int r = 0; r < 4; r++) {
                        int jl = jm * 16 + quad * 4 + r;
                        int ql = w * 32 + qn * 16 + l16;
                        if (jl > ql) S[jm][qn][r] = -1e30f;
                    }
        }

        // online softmax (state per q col = l16, replicated across quads)
        float alpha[2];
        #pragma unroll
        for (int qn = 0; qn < 2; qn++) {
            float tmax = -INFINITY;
            #pragma unroll
            for (int jm = 0; jm < 8; jm++)
                #pragma unroll
                for (int r = 0; r < 4; r++)
                    tmax = fmaxf(tmax, S[jm][qn][r]);
            tmax = fmaxf(tmax, __shfl_xor(tmax, 16));
            tmax = fmaxf(tmax, __shfl_xor(tmax, 32));
            tmax *= scale;
            float mnew = fmaxf(m_r[qn], tmax);
            alpha[qn] = __expf(m_r[qn] - mnew);
            m_r[qn] = mnew;
            float rsum = 0.0f;
            #pragma unroll
            for (int jm = 0; jm < 8; jm++)
                #pragma unroll
                for (int r = 0; r < 4; r++) {
                    float p = __expf(S[jm][qn][r] * scale - mnew);
                    S[jm][qn][r] = p;
                    rsum += p;
                }
            rsum += __shfl_xor(rsum, 16);
            rsum += __shfl_xor(rsum, 32);
            l_r[qn] = l_r[qn] * alpha[qn] + rsum;
        }

        // P -> LDS (per-wave private): Ps[q_local][j], b64 writes (4 consec j)
        #pragma unroll
        for (int jm = 0; jm < 8; jm++)
            #pragma unroll
            for (int qn = 0; qn < 2; qn++) {
                f16x4 pk;
                pk.x = (f16)S[jm][qn][0];
                pk.y = (f16)S[jm][qn][1];
                pk.z = (f16)S[jm][qn][2];
                pk.w = (f16)S[jm][qn][3];
                *(f16x4*)(Ps + (size_t)(qn * 16 + l16) * 136 + jm * 16 + quad * 4) = pk;
            }

        // rescale O by alpha (redistribute per-row via shuffle)
        float aPV[2][4];
        #pragma unroll
        for (int m = 0; m < 2; m++)
            #pragma unroll
            for (int r = 0; r < 4; r++)
                aPV[m][r] = __shfl(alpha[m], quad * 20 + r);
        #pragma unroll
        for (int m = 0; m < 2; m++)
            #pragma unroll
            for (int n = 0; n < 4; n++)
                #pragma unroll
                for (int r = 0; r < 4; r++)
                    Oacc[m][n][r] *= aPV[m][r];

        // O += P V : A = P (m=q, k=j), B = V^T-as-B (k=j, n=d)
        #pragma unroll
        for (int kblk = 0; kblk < 4; kblk++) {
            f16x8 pf[2];
            #pragma unroll
            for (int m = 0; m < 2; m++)
                pf[m] = *(const f16x8*)(Ps + (size_t)(m * 16 + l16) * 136 +
                                        kblk * 32 + quad * 8);
            f16x8 vf[4];
            #pragma unroll
            for (int n = 0; n < 4; n++) {
                int d = n * 16 + l16;
                int g = (kblk * 4 + quad);
                int gs = (g & 8) | ((g ^ d) & 7);
                vf[n] = *(const f16x8*)(Vs + (size_t)(d * 16 + gs) * 8);
            }
            #pragma unroll
            for (int m = 0; m < 2; m++)
                #pragma unroll
                for (int n = 0; n < 4; n++)
                    Oacc[m][n] = __builtin_amdgcn_mfma_f32_16x16x32_f16(
                        pf[m], vf[n], Oacc[m][n], 0, 0, 0);
        }
    }

    // epilogue: O / l, store f16 to ybuf [B,T,C]
    #pragma unroll
    for (int m = 0; m < 2; m++) {
        float lPV[4];
        #pragma unroll
        for (int r = 0; r < 4; r++)
            lPV[r] = 1.0f / __shfl(l_r[m], quad * 20 + r);
        #pragma unroll
        for (int n = 0; n < 4; n++) {
            #pragma unroll
            for (int r = 0; r < 4; r++) {
                int q = q0 + w * 32 + m * 16 + quad * 4 + r;
                y[(size_t)(b * T_SEQ + q) * N_EMB + h * 64 + n * 16 + l16] =
                    (f16)(Oacc[m][n][r] * lPV[r]);
            }
        }
    }
}

// ---------------------------------------------------------------- launch
extern "C" void kernel_launch(void* const* d_in, const int* in_sizes, int n_in,
                              void* d_out, int out_size, void* d_ws, size_t ws_size,
                              hipStream_t stream) {
    const float* x      = (const float*)d_in[0];
    const float* ln1_g  = (const float*)d_in[1];
    const float* ln1_b  = (const float*)d_in[2];
    const float* w_attn = (const float*)d_in[3];
    const float* b_attn = (const float*)d_in[4];
    const float* w_proj = (const float*)d_in[5];
    const float* b_proj = (const float*)d_in[6];
    const float* ln2_g  = (const float*)d_in[7];
    const float* ln2_b  = (const float*)d_in[8];
    const float* w_fc   = (const float*)d_in[9];
    const float* b_fc   = (const float*)d_in[10];
    const float* w_fc2  = (const float*)d_in[11];
    const float* b_fc2  = (const float*)d_in[12];
    float* out = (float*)d_out;

    const size_t MB = 1024 * 1024;
    char* ws = (char*)d_ws;
    f16*   lnbuf = (f16*)ws;                        // 16 MB
    f16*   qkbuf = (f16*)(ws + 16 * MB);            // 32 MB: [M][2048] Q|K
    f16*   vTbuf = (f16*)(ws + 48 * MB);            // 16 MB: [b][h][d][t]
    f16*   ybuf  = (f16*)(ws + 64 * MB);            // 16 MB
    f16*   h     = (f16*)(ws + 80 * MB);            // 64 MB
    f16*   wT    = (f16*)(ws + 144 * MB);           // 26 MB
    f16* wT_attn = wT;
    f16* wT_proj = wT_attn + (size_t)3072 * 1024;
    f16* wT_fc   = wT_proj + (size_t)1024 * 1024;
    f16* wT_fc2  = wT_fc   + (size_t)1024 * 4096;

    wconv_kernel<<<dim3(3072 / 32, 1024 / 32), 256, 0, stream>>>(w_attn, wT_attn, 1024, 3072);
    wconv_kernel<<<dim3(1024 / 32, 1024 / 32), 256, 0, stream>>>(w_proj, wT_proj, 1024, 1024);
    wconv_kernel<<<dim3(4096 / 32, 1024 / 32), 256, 0, stream>>>(w_fc,   wT_fc,   1024, 4096);
    wconv_kernel<<<dim3(1024 / 32, 4096 / 32), 256, 0, stream>>>(w_fc2,  wT_fc2,  4096, 1024);

    ln_kernel<<<M_ROWS, 256, 0, stream>>>(x, ln1_g, ln1_b, lnbuf);
    gemm_f16<3><<<dim3(3072 / 128, M_ROWS / 128), 256, 0, stream>>>(
        lnbuf, wT_attn, b_attn, nullptr, nullptr, qkbuf, vTbuf, 1024, 3072);
    flash_kernel<<<dim3(16, 64), 256, 0, stream>>>(qkbuf, vTbuf, ybuf);
    gemm_f16<1><<<dim3(1024 / 128, M_ROWS / 128), 256, 0, stream>>>(
        ybuf, wT_proj, b_proj, x, out, nullptr, nullptr, 1024, 1024);
    ln_kernel<<<M_ROWS, 256, 0, stream>>>(out, ln2_g, ln2_b, lnbuf);
    gemm_f16<2><<<dim3(4096 / 128, M_ROWS / 128), 256, 0, stream>>>(
        lnbuf, wT_fc, b_fc, nullptr, nullptr, h, nullptr, 1024, 4096);
    gemm_f16<1><<<dim3(1024 / 128, M_ROWS / 128), 256, 0, stream>>>(
        h, wT_fc2, b_fc2, out, out, nullptr, nullptr, 4096, 1024);
}